// Round 5
// baseline (646.282 us; speedup 1.0000x reference)
//
#include <hip/hip_runtime.h>
#include <hip/hip_bf16.h>

#define N_NODES 100000
#define N_EDGES 1000000
#define SCAN_CHUNK 1024
#define N_SCAN_BLKS ((N_NODES + SCAN_CHUNK - 1) / SCAN_CHUNK)   // 98
#define NPB 128      // sorted positions per block in msg_kernel
#define HST 68       // LDS row stride (f32): 68%32=4 -> <=2-way conflicts, free
#define PQ_BLKS 1563
#define EFB_BLKS 2048

typedef __bf16 bf16x8 __attribute__((ext_vector_type(8)));
typedef float  f32x4  __attribute__((ext_vector_type(4)));

#define MFMA(a, b, c) __builtin_amdgcn_mfma_f32_16x16x32_bf16((a), (b), (c), 0, 0, 0)

__device__ __forceinline__ float sigmoid_f(float x) { return 1.f / (1.f + __expf(-x)); }
__device__ __forceinline__ float tanh_f(float x) {
    float cx = fminf(fmaxf(x, -30.f), 30.f);
    float e = __expf(-2.f * cx);
    return (1.f - e) / (1.f + e);
}

// ---------------------------------------------------------------------------
// Fused precompute (one dispatch, block-range split):
//  blocks [0, PQ_BLKS):            P/Q = nf @ W1[:,0:128]^T (+b1), bf16 out
//  blocks [PQ_BLKS, +EFB_BLKS):    efb = bf16(ef)  (sequential convert)
//  last block:                     M = w_ih@W2, b2i = w_ih@b2
// ---------------------------------------------------------------------------
__global__ __launch_bounds__(256) void pre_kernel(
    const float* __restrict__ nf, const float* __restrict__ W1,
    const float* __restrict__ b1, const float* __restrict__ ef,
    const float* __restrict__ w_ih, const float* __restrict__ W2,
    const float* __restrict__ b2,
    __bf16* __restrict__ Pb, __bf16* __restrict__ Qb,
    __bf16* __restrict__ efb, float* __restrict__ M, float* __restrict__ b2i)
{
    const int b = blockIdx.x;
    if (b < PQ_BLKS) {
        const int lane = threadIdx.x & 63;
        const int r = lane & 15, g = lane >> 4;
        bf16x8 Bs[4][2], Bd[4][2];
        #pragma unroll
        for (int nt = 0; nt < 4; ++nt)
            #pragma unroll
            for (int kk = 0; kk < 2; ++kk) {
                const float* ws = &W1[(nt * 16 + r) * 160 + kk * 32 + g * 8];
                const float* wd = ws + 64;
                f32x4 s0 = *(const f32x4*)ws, s1 = *(const f32x4*)(ws + 4);
                f32x4 d0 = *(const f32x4*)wd, d1 = *(const f32x4*)(wd + 4);
                #pragma unroll
                for (int j = 0; j < 4; ++j) {
                    Bs[nt][kk][j] = (__bf16)s0[j]; Bs[nt][kk][j + 4] = (__bf16)s1[j];
                    Bd[nt][kk][j] = (__bf16)d0[j]; Bd[nt][kk][j + 4] = (__bf16)d1[j];
                }
            }
        float b1v[4];
        #pragma unroll
        for (int nt = 0; nt < 4; ++nt) b1v[nt] = b1[nt * 16 + r];

        const int wid = b * 4 + (threadIdx.x >> 6);
        const int nW  = PQ_BLKS * 4;
        for (int t = wid; t < N_NODES / 16; t += nW) {
            const int base = t * 16;
            bf16x8 A[2];
            #pragma unroll
            for (int kk = 0; kk < 2; ++kk) {
                const float* p = &nf[(size_t)(base + r) * 64 + kk * 32 + g * 8];
                f32x4 v0 = *(const f32x4*)p, v1 = *(const f32x4*)(p + 4);
                #pragma unroll
                for (int j = 0; j < 4; ++j) { A[kk][j] = (__bf16)v0[j]; A[kk][j + 4] = (__bf16)v1[j]; }
            }
            f32x4 accP[4] = {}, accQ[4] = {};
            #pragma unroll
            for (int nt = 0; nt < 4; ++nt)
                #pragma unroll
                for (int kk = 0; kk < 2; ++kk) {
                    accP[nt] = MFMA(A[kk], Bs[nt][kk], accP[nt]);
                    accQ[nt] = MFMA(A[kk], Bd[nt][kk], accQ[nt]);
                }
            #pragma unroll
            for (int nt = 0; nt < 4; ++nt)
                #pragma unroll
                for (int rr = 0; rr < 4; ++rr) {
                    const int node = base + g * 4 + rr;
                    const int col  = nt * 16 + r;
                    Pb[(size_t)node * 64 + col] = (__bf16)(accP[nt][rr] + b1v[nt]);
                    Qb[(size_t)node * 64 + col] = (__bf16)accQ[nt][rr];
                }
        }
    } else if (b < PQ_BLKS + EFB_BLKS) {
        // convert ef (32 f32/row) to bf16, 8 floats per thread-iter
        const int tid = (b - PQ_BLKS) * 256 + threadIdx.x;
        const int stride = EFB_BLKS * 256;
        const int total = N_EDGES * 32 / 8;   // 4M
        for (int i = tid; i < total; i += stride) {
            const float* p = ef + (size_t)i * 8;
            f32x4 v0 = *(const f32x4*)p, v1 = *(const f32x4*)(p + 4);
            bf16x8 v;
            #pragma unroll
            for (int j = 0; j < 4; ++j) { v[j] = (__bf16)v0[j]; v[j + 4] = (__bf16)v1[j]; }
            *(bf16x8*)&efb[(size_t)i * 8] = v;
        }
    } else {
        for (int tid = threadIdx.x; tid < 192 * 64; tid += 256) {
            int d = tid >> 6, k = tid & 63;
            float s = 0.f;
            #pragma unroll 8
            for (int j = 0; j < 64; ++j) s += w_ih[d * 64 + j] * W2[j * 64 + k];
            M[tid] = s;
        }
        for (int tid = threadIdx.x; tid < 192; tid += 256) {
            float s = 0.f;
            for (int j = 0; j < 64; ++j) s += w_ih[tid * 64 + j] * b2[j];
            b2i[tid] = s;
        }
    }
}

// ---------------------------------------------------------------------------
// Histogram of dst
// ---------------------------------------------------------------------------
__global__ __launch_bounds__(256) void hist_kernel(
    const int* __restrict__ ei, int* __restrict__ cnt)
{
    const int* dstI = ei + N_EDGES;
    for (int e = blockIdx.x * blockDim.x + threadIdx.x; e < N_EDGES;
         e += gridDim.x * blockDim.x)
        atomicAdd(&cnt[dstI[e]], 1);
}

__global__ __launch_bounds__(256) void scanA_kernel(
    const int* __restrict__ cnt, int* __restrict__ blkSum)
{
    const int lane = threadIdx.x & 63, w = threadIdx.x >> 6;
    int base = blockIdx.x * SCAN_CHUNK + threadIdx.x * 4;
    int s = 0;
    #pragma unroll
    for (int j = 0; j < 4; ++j) if (base + j < N_NODES) s += cnt[base + j];
    #pragma unroll
    for (int o = 32; o > 0; o >>= 1) s += __shfl_down(s, o);
    __shared__ int wt[4];
    if (lane == 0) wt[w] = s;
    __syncthreads();
    if (threadIdx.x == 0) blkSum[blockIdx.x] = wt[0] + wt[1] + wt[2] + wt[3];
}

__global__ void scanB_kernel(int* __restrict__ blkSum)
{
    const int lane = threadIdx.x;
    int carry = 0;
    for (int c = 0; c < N_SCAN_BLKS; c += 64) {
        int v = (c + lane < N_SCAN_BLKS) ? blkSum[c + lane] : 0;
        int inc = v;
        #pragma unroll
        for (int o = 1; o < 64; o <<= 1) {
            int t = __shfl_up(inc, o);
            if (lane >= o) inc += t;
        }
        int ex = inc - v;
        if (c + lane < N_SCAN_BLKS) blkSum[c + lane] = carry + ex;
        carry += __shfl(inc, 63);
    }
}

__global__ __launch_bounds__(256) void scanC_kernel(
    const int* __restrict__ cnt, const int* __restrict__ blkSum,
    int* __restrict__ off, int* __restrict__ cur)
{
    const int lane = threadIdx.x & 63, w = threadIdx.x >> 6;
    int base = blockIdx.x * SCAN_CHUNK + threadIdx.x * 4;
    int v[4];
    int tsum = 0;
    #pragma unroll
    for (int j = 0; j < 4; ++j) {
        v[j] = (base + j < N_NODES) ? cnt[base + j] : 0;
        tsum += v[j];
    }
    int inc = tsum;
    #pragma unroll
    for (int o = 1; o < 64; o <<= 1) {
        int t = __shfl_up(inc, o);
        if (lane >= o) inc += t;
    }
    __shared__ int wt[4];
    if (lane == 63) wt[w] = inc;
    __syncthreads();
    int woff = 0;
    for (int k = 0; k < w; ++k) woff += wt[k];
    int running = blkSum[blockIdx.x] + woff + inc - tsum;
    #pragma unroll
    for (int j = 0; j < 4; ++j) {
        if (base + j < N_NODES) {
            off[base + j] = running;
            cur[base + j] = running;
            if (base + j == N_NODES - 1) off[N_NODES] = running + v[j];
            running += v[j];
        }
    }
}

// ---------------------------------------------------------------------------
// Scatter: pos = cur[dst]++; slots[pos] = (src, e)
// ---------------------------------------------------------------------------
__global__ __launch_bounds__(256) void scatter_kernel(
    const int* __restrict__ ei, int* __restrict__ cur,
    int2* __restrict__ slots)
{
    const int* srcI = ei;
    const int* dstI = ei + N_EDGES;
    for (int e = blockIdx.x * blockDim.x + threadIdx.x; e < N_EDGES;
         e += gridDim.x * blockDim.x) {
        int p = atomicAdd(&cur[dstI[e]], 1);
        slots[p] = make_int2(srcI[e], e);
    }
}

// ---------------------------------------------------------------------------
// Fused message kernel over dst-sorted positions (NPB=128/block).
// Phase A: T = efb@W1e^T via MFMA -> LDS h (f32). Two independent tiles per
// wave for miss overlap; efb row = one 64B line.
// Phase B: per node, acc = sum relu(h + P[src] + Q[n]); plain store when the
// node's range is block-contained, else atomicAdd (Hsum pre-zeroed).
// ---------------------------------------------------------------------------
__global__ __launch_bounds__(256) void msg_kernel(
    const int* __restrict__ offA, const int2* __restrict__ slots,
    const __bf16* __restrict__ efb, const float* __restrict__ W1,
    const __bf16* __restrict__ Pb, const __bf16* __restrict__ Qb,
    float* __restrict__ Hsum)
{
    __shared__ float h[NPB * HST];   // 34.8 KiB -> 4 blocks/CU
    __shared__ int nlo_s;
    const int p0 = blockIdx.x * NPB;
    const int p1 = min(p0 + NPB, N_EDGES);
    const int cntP = p1 - p0;
    const int lane = threadIdx.x & 63;
    const int w = threadIdx.x >> 6;
    const int r = lane & 15, g = lane >> 4;

    bf16x8 Be[4];
    #pragma unroll
    for (int nt = 0; nt < 4; ++nt) {
        const float* wp = &W1[(nt * 16 + r) * 160 + 128 + g * 8];
        f32x4 w0 = *(const f32x4*)wp, w1 = *(const f32x4*)(wp + 4);
        #pragma unroll
        for (int j = 0; j < 4; ++j) { Be[nt][j] = (__bf16)w0[j]; Be[nt][j + 4] = (__bf16)w1[j]; }
    }

    if (threadIdx.x == 0) {
        int lo = 0, hi = N_NODES - 1;
        while (lo < hi) { int mid = (lo + hi) >> 1; if (offA[mid + 1] > p0) hi = mid; else lo = mid + 1; }
        nlo_s = lo;
    }

    // ---- phase A: 8 tiles, 2 per wave, loads issued as 2 independent chains
    const int ntile = cntP >> 4;
    int2 sl0, sl1;
    const int t0 = w, t1 = w + 4;
    if (t0 < ntile) sl0 = slots[p0 + t0 * 16 + r];
    if (t1 < ntile) sl1 = slots[p0 + t1 * 16 + r];
    bf16x8 e0, e1;
    if (t0 < ntile) e0 = *(const bf16x8*)&efb[(size_t)sl0.y * 32 + g * 8];
    if (t1 < ntile) e1 = *(const bf16x8*)&efb[(size_t)sl1.y * 32 + g * 8];
    if (t0 < ntile) {
        f32x4 accT[4] = {};
        #pragma unroll
        for (int nt = 0; nt < 4; ++nt) accT[nt] = MFMA(e0, Be[nt], accT[nt]);
        #pragma unroll
        for (int nt = 0; nt < 4; ++nt)
            #pragma unroll
            for (int rr = 0; rr < 4; ++rr)
                h[(t0 * 16 + g * 4 + rr) * HST + nt * 16 + r] = accT[nt][rr];
    }
    if (t1 < ntile) {
        f32x4 accT[4] = {};
        #pragma unroll
        for (int nt = 0; nt < 4; ++nt) accT[nt] = MFMA(e1, Be[nt], accT[nt]);
        #pragma unroll
        for (int nt = 0; nt < 4; ++nt)
            #pragma unroll
            for (int rr = 0; rr < 4; ++rr)
                h[(t1 * 16 + g * 4 + rr) * HST + nt * 16 + r] = accT[nt][rr];
    }
    __syncthreads();

    // ---- phase B ----
    const int nlo = nlo_s;
    for (int n = nlo + w; n < N_NODES; n += 4) {
        const int on0 = offA[n], on1 = offA[n + 1];
        if (on0 >= p1) break;
        const int lo_ = max(on0, p0), hi_ = min(on1, p1);
        const int m = hi_ - lo_;
        if (m <= 0) continue;
        const int lb = lo_ - p0;
        float q = (float)Qb[(size_t)n * 64 + lane];
        float acc = 0.f;
        int sl = (lane < m) ? slots[lo_ + lane].x : 0;
        int i = 0;
        for (; i + 8 <= m; i += 8) {
            float pv[8], hv[8];
            #pragma unroll
            for (int j = 0; j < 8; ++j) {
                int s = __shfl(sl, i + j);
                pv[j] = (float)Pb[(size_t)s * 64 + lane];
                hv[j] = h[(lb + i + j) * HST + lane];
            }
            #pragma unroll
            for (int j = 0; j < 8; ++j)
                acc += fmaxf(hv[j] + pv[j] + q, 0.f);
        }
        for (; i < m; ++i) {
            int s = __shfl(sl, i);   // m <= NPB=128 but degree max ~35 < 64
            acc += fmaxf(h[(lb + i) * HST + lane] + (float)Pb[(size_t)s * 64 + lane] + q, 0.f);
        }
        if (on0 >= p0 && on1 <= p1) Hsum[(size_t)n * 64 + lane] = acc;
        else                        atomicAdd(&Hsum[(size_t)n * 64 + lane], acc);
    }
}

// ---------------------------------------------------------------------------
// GRU (weights in LDS as bf16, XOR-swizzled; split-bf16 A hi+lo)
// ---------------------------------------------------------------------------
__global__ __launch_bounds__(256) void gru_kernel(
    const float* __restrict__ nf, const float* __restrict__ Hsum,
    const float* __restrict__ M, const float* __restrict__ w_hh,
    const float* __restrict__ b_ih, const float* __restrict__ b_hh,
    const float* __restrict__ b2i, const int* __restrict__ cnt,
    float* __restrict__ out)
{
    __shared__ __bf16 w_lds[2 * 192 * 64];
    for (int ch = threadIdx.x; ch < 3072; ch += 256) {
        int mat = ch / 1536;
        int rr  = (ch - mat * 1536) >> 3;
        int cc  = ch & 7;
        const float* sp = (mat == 0 ? M : w_hh) + rr * 64 + cc * 8;
        f32x4 a = *(const f32x4*)sp, b = *(const f32x4*)(sp + 4);
        bf16x8 v;
        #pragma unroll
        for (int j = 0; j < 4; ++j) { v[j] = (__bf16)a[j]; v[j + 4] = (__bf16)b[j]; }
        *(bf16x8*)&w_lds[((mat * 192 + rr) * 64) + ((cc ^ (rr & 7)) * 8)] = v;
    }
    __syncthreads();

    const int lane = threadIdx.x & 63;
    const int r = lane & 15, g = lane >> 4;
    const int wid = blockIdx.x * (blockDim.x >> 6) + (threadIdx.x >> 6);
    const int nW  = gridDim.x * (blockDim.x >> 6);

    float br[4], bz[4], bin_[4], bhn_[4], c2r[4], c2z[4], c2n[4];
    #pragma unroll
    for (int nt = 0; nt < 4; ++nt) {
        const int d = nt * 16 + r;
        br[nt]   = b_ih[d] + b_hh[d];
        bz[nt]   = b_ih[64 + d] + b_hh[64 + d];
        bin_[nt] = b_ih[128 + d];
        bhn_[nt] = b_hh[128 + d];
        c2r[nt] = b2i ? b2i[d] : 0.f;
        c2z[nt] = b2i ? b2i[64 + d] : 0.f;
        c2n[nt] = b2i ? b2i[128 + d] : 0.f;
    }
    const int swz = r & 7;

    for (int t = wid; t < N_NODES / 16; t += nW) {
        const int base = t * 16;
        bf16x8 aaH[2], aaL[2], ahH[2], ahL[2];
        #pragma unroll
        for (int kk = 0; kk < 2; ++kk) {
            const float* pa = &Hsum[(size_t)(base + r) * 64 + kk * 32 + g * 8];
            const float* ph = &nf  [(size_t)(base + r) * 64 + kk * 32 + g * 8];
            f32x4 a0 = *(const f32x4*)pa, a1 = *(const f32x4*)(pa + 4);
            f32x4 h0 = *(const f32x4*)ph, h1 = *(const f32x4*)(ph + 4);
            #pragma unroll
            for (int j = 0; j < 4; ++j) {
                float av0 = a0[j], av1 = a1[j], hv0 = h0[j], hv1 = h1[j];
                __bf16 x;
                x = (__bf16)av0; aaH[kk][j]     = x; aaL[kk][j]     = (__bf16)(av0 - (float)x);
                x = (__bf16)av1; aaH[kk][j + 4] = x; aaL[kk][j + 4] = (__bf16)(av1 - (float)x);
                x = (__bf16)hv0; ahH[kk][j]     = x; ahL[kk][j]     = (__bf16)(hv0 - (float)x);
                x = (__bf16)hv1; ahH[kk][j + 4] = x; ahL[kk][j + 4] = (__bf16)(hv1 - (float)x);
            }
        }

        f32x4 accR[4] = {}, accZ[4] = {}, accIN[4] = {}, accHN[4] = {};
        #pragma unroll
        for (int c = 0; c < 3; ++c)
            #pragma unroll
            for (int nt = 0; nt < 4; ++nt) {
                const int row = c * 64 + nt * 16 + r;
                f32x4 ai = {}, ah = {};
                #pragma unroll
                for (int kk = 0; kk < 2; ++kk) {
                    const int cc = (kk * 4 + g) ^ swz;
                    bf16x8 Bi = *(const bf16x8*)&w_lds[row * 64 + cc * 8];
                    bf16x8 Bh = *(const bf16x8*)&w_lds[(192 + row) * 64 + cc * 8];
                    ai = MFMA(aaH[kk], Bi, ai);
                    ai = MFMA(aaL[kk], Bi, ai);
                    ah = MFMA(ahH[kk], Bh, ah);
                    ah = MFMA(ahL[kk], Bh, ah);
                }
                if (c == 0)      accR[nt] = ai + ah;
                else if (c == 1) accZ[nt] = ai + ah;
                else             { accIN[nt] = ai; accHN[nt] = ah; }
            }
        #pragma unroll
        for (int nt = 0; nt < 4; ++nt)
            #pragma unroll
            for (int rr = 0; rr < 4; ++rr) {
                const int node = base + g * 4 + rr;
                const int d    = nt * 16 + r;
                float dg = cnt ? (float)cnt[node] : 0.f;
                float rg = sigmoid_f(accR[nt][rr] + br[nt] + dg * c2r[nt]);
                float zg = sigmoid_f(accZ[nt][rr] + bz[nt] + dg * c2z[nt]);
                float ng = tanh_f(accIN[nt][rr] + bin_[nt] + dg * c2n[nt] +
                                  rg * (accHN[nt][rr] + bhn_[nt]));
                float hv = nf[(size_t)node * 64 + d];
                out[(size_t)node * 64 + d] = (1.f - zg) * ng + zg * hv;
            }
    }
}

// ---------------------------------------------------------------------------
// Fallback path kernels (unused when ws is large enough)
// ---------------------------------------------------------------------------
__global__ __launch_bounds__(256) void pq_kernel_fb(
    const float* __restrict__ nf, const float* __restrict__ W1,
    const float* __restrict__ b1,
    __bf16* __restrict__ Pb, __bf16* __restrict__ Qb)
{
    const int lane = threadIdx.x & 63;
    const int r = lane & 15, g = lane >> 4;
    bf16x8 Bs[4][2], Bd[4][2];
    #pragma unroll
    for (int nt = 0; nt < 4; ++nt)
        #pragma unroll
        for (int kk = 0; kk < 2; ++kk) {
            const float* ws = &W1[(nt * 16 + r) * 160 + kk * 32 + g * 8];
            const float* wd = ws + 64;
            f32x4 s0 = *(const f32x4*)ws, s1 = *(const f32x4*)(ws + 4);
            f32x4 d0 = *(const f32x4*)wd, d1 = *(const f32x4*)(wd + 4);
            #pragma unroll
            for (int j = 0; j < 4; ++j) {
                Bs[nt][kk][j] = (__bf16)s0[j]; Bs[nt][kk][j + 4] = (__bf16)s1[j];
                Bd[nt][kk][j] = (__bf16)d0[j]; Bd[nt][kk][j + 4] = (__bf16)d1[j];
            }
        }
    float b1v[4];
    #pragma unroll
    for (int nt = 0; nt < 4; ++nt) b1v[nt] = b1[nt * 16 + r];
    const int wid = blockIdx.x * 4 + (threadIdx.x >> 6);
    const int nW  = gridDim.x * 4;
    for (int t = wid; t < N_NODES / 16; t += nW) {
        const int base = t * 16;
        bf16x8 A[2];
        #pragma unroll
        for (int kk = 0; kk < 2; ++kk) {
            const float* p = &nf[(size_t)(base + r) * 64 + kk * 32 + g * 8];
            f32x4 v0 = *(const f32x4*)p, v1 = *(const f32x4*)(p + 4);
            #pragma unroll
            for (int j = 0; j < 4; ++j) { A[kk][j] = (__bf16)v0[j]; A[kk][j + 4] = (__bf16)v1[j]; }
        }
        f32x4 accP[4] = {}, accQ[4] = {};
        #pragma unroll
        for (int nt = 0; nt < 4; ++nt)
            #pragma unroll
            for (int kk = 0; kk < 2; ++kk) {
                accP[nt] = MFMA(A[kk], Bs[nt][kk], accP[nt]);
                accQ[nt] = MFMA(A[kk], Bd[nt][kk], accQ[nt]);
            }
        #pragma unroll
        for (int nt = 0; nt < 4; ++nt)
            #pragma unroll
            for (int rr = 0; rr < 4; ++rr) {
                const int node = base + g * 4 + rr;
                const int col  = nt * 16 + r;
                Pb[(size_t)node * 64 + col] = (__bf16)(accP[nt][rr] + b1v[nt]);
                Qb[(size_t)node * 64 + col] = (__bf16)accQ[nt][rr];
            }
    }
}

#define LDH 68
__global__ __launch_bounds__(256) void edge_kernel_fb(
    const int* __restrict__ ei, const float* __restrict__ ef,
    const float* __restrict__ W1, const float* __restrict__ W2,
    const float* __restrict__ b2,
    const __bf16* __restrict__ Pb, const __bf16* __restrict__ Qb,
    float* __restrict__ agg)
{
    __shared__ float lds_h[4][16 * LDH];
    const int lane = threadIdx.x & 63;
    const int r = lane & 15, g = lane >> 4;
    float* hb = lds_h[threadIdx.x >> 6];
    const int* srcI = ei;
    const int* dstI = ei + N_EDGES;
    bf16x8 Be[4];
    #pragma unroll
    for (int nt = 0; nt < 4; ++nt) {
        const float* wp = &W1[(nt * 16 + r) * 160 + 128 + g * 8];
        f32x4 w0 = *(const f32x4*)wp, w1 = *(const f32x4*)(wp + 4);
        #pragma unroll
        for (int j = 0; j < 4; ++j) { Be[nt][j] = (__bf16)w0[j]; Be[nt][j + 4] = (__bf16)w1[j]; }
    }
    bf16x8 B2[4][2];
    #pragma unroll
    for (int nt = 0; nt < 4; ++nt)
        #pragma unroll
        for (int kk = 0; kk < 2; ++kk) {
            const float* wp = &W2[(nt * 16 + r) * 64 + kk * 32 + g * 8];
            f32x4 w0 = *(const f32x4*)wp, w1 = *(const f32x4*)(wp + 4);
            #pragma unroll
            for (int j = 0; j < 4; ++j) { B2[nt][kk][j] = (__bf16)w0[j]; B2[nt][kk][j + 4] = (__bf16)w1[j]; }
        }
    float b2v[4];
    #pragma unroll
    for (int nt = 0; nt < 4; ++nt) b2v[nt] = b2[nt * 16 + r];
    const int wid = blockIdx.x * 4 + (threadIdx.x >> 6);
    const int nW  = gridDim.x * 4;
    for (int t = wid; t < N_EDGES / 16; t += nW) {
        const int base = t * 16;
        const int er = base + r;
        const int es = srcI[er], ed = dstI[er];
        bf16x8 Ae;
        {
            const float* p = &ef[(size_t)er * 32 + g * 8];
            f32x4 v0 = *(const f32x4*)p, v1 = *(const f32x4*)(p + 4);
            #pragma unroll
            for (int j = 0; j < 4; ++j) { Ae[j] = (__bf16)v0[j]; Ae[j + 4] = (__bf16)v1[j]; }
        }
        f32x4 accT[4] = {};
        #pragma unroll
        for (int nt = 0; nt < 4; ++nt) accT[nt] = MFMA(Ae, Be[nt], accT[nt]);
        #pragma unroll
        for (int nt = 0; nt < 4; ++nt)
            #pragma unroll
            for (int rr = 0; rr < 4; ++rr)
                hb[(g * 4 + rr) * LDH + nt * 16 + r] = accT[nt][rr];
        bf16x8 A2[2];
        #pragma unroll
        for (int kk = 0; kk < 2; ++kk) {
            const int k = kk * 32 + g * 8;
            const float* hp = &hb[r * LDH + k];
            f32x4 h0 = *(const f32x4*)hp, h1 = *(const f32x4*)(hp + 4);
            bf16x8 p8 = *(const bf16x8*)(Pb + (size_t)es * 64 + k);
            bf16x8 q8 = *(const bf16x8*)(Qb + (size_t)ed * 64 + k);
            #pragma unroll
            for (int j = 0; j < 4; ++j) {
                A2[kk][j]     = (__bf16)fmaxf(h0[j] + (float)p8[j]     + (float)q8[j],     0.f);
                A2[kk][j + 4] = (__bf16)fmaxf(h1[j] + (float)p8[j + 4] + (float)q8[j + 4], 0.f);
            }
        }
        f32x4 accM[4] = {};
        #pragma unroll
        for (int nt = 0; nt < 4; ++nt)
            #pragma unroll
            for (int kk = 0; kk < 2; ++kk)
                accM[nt] = MFMA(A2[kk], B2[nt][kk], accM[nt]);
        int4 d4 = *(const int4*)(dstI + base + g * 4);
        const int* dd = (const int*)&d4;
        #pragma unroll
        for (int rr = 0; rr < 4; ++rr) {
            float* dp = agg + (size_t)dd[rr] * 64;
            #pragma unroll
            for (int nt = 0; nt < 4; ++nt)
                atomicAdd(dp + nt * 16 + r, accM[nt][rr] + b2v[nt]);
        }
    }
}

extern "C" void kernel_launch(void* const* d_in, const int* in_sizes, int n_in,
                              void* d_out, int out_size, void* d_ws, size_t ws_size,
                              hipStream_t stream) {
    const float* nf  = (const float*)d_in[0];
    const int*   ei  = (const int*)  d_in[1];
    const float* ef  = (const float*)d_in[2];
    const float* W1  = (const float*)d_in[3];
    const float* b1  = (const float*)d_in[4];
    const float* W2  = (const float*)d_in[5];
    const float* b2  = (const float*)d_in[6];
    const float* wih = (const float*)d_in[7];
    const float* whh = (const float*)d_in[8];
    const float* bih = (const float*)d_in[9];
    const float* bhh = (const float*)d_in[10];
    float* out = (float*)d_out;

    char* ws = (char*)d_ws;
    size_t off_b = 0;
    auto alloc = [&](size_t bytes) { char* p = ws + off_b; off_b = (off_b + bytes + 255) & ~(size_t)255; return p; };
    int*    cnt     = (int*)   alloc((size_t)N_NODES * 4);
    int*    offA    = (int*)   alloc((size_t)(N_NODES + 1) * 4);
    int*    cur     = (int*)   alloc((size_t)N_NODES * 4);
    int*    blkSum  = (int*)   alloc((size_t)N_SCAN_BLKS * 4);
    int2*   slots   = (int2*)  alloc((size_t)N_EDGES * 8);        // 8 MB
    __bf16* efb     = (__bf16*)alloc((size_t)N_EDGES * 32 * 2);   // 64 MB
    __bf16* Pb      = (__bf16*)alloc((size_t)N_NODES * 64 * 2);   // 12.8 MB
    __bf16* Qb      = (__bf16*)alloc((size_t)N_NODES * 64 * 2);
    float*  Hsum    = (float*) alloc((size_t)N_NODES * 64 * 4);   // 25.6 MB
    float*  M       = (float*) alloc((size_t)192 * 64 * 4);
    float*  b2i     = (float*) alloc((size_t)192 * 4);
    const size_t need = off_b;

    if (ws_size >= need) {
        hipMemsetAsync(cnt, 0, (size_t)N_NODES * 4, stream);
        hipMemsetAsync(Hsum, 0, (size_t)N_NODES * 64 * 4, stream);
        hist_kernel   <<<1024, 256, 0, stream>>>(ei, cnt);
        scanA_kernel  <<<N_SCAN_BLKS, 256, 0, stream>>>(cnt, blkSum);
        scanB_kernel  <<<1, 64, 0, stream>>>(blkSum);
        scanC_kernel  <<<N_SCAN_BLKS, 256, 0, stream>>>(cnt, blkSum, offA, cur);
        scatter_kernel<<<1024, 256, 0, stream>>>(ei, cur, slots);
        pre_kernel    <<<PQ_BLKS + EFB_BLKS + 1, 256, 0, stream>>>(
                          nf, W1, b1, ef, wih, W2, b2, Pb, Qb, efb, M, b2i);
        msg_kernel    <<<(N_EDGES + NPB - 1) / NPB, 256, 0, stream>>>(
                          offA, slots, efb, W1, Pb, Qb, Hsum);
        gru_kernel    <<<1563, 256, 0, stream>>>(nf, Hsum, M, whh, bih, bhh, b2i, cnt, out);
    } else {
        float*  agg = (float*)ws;
        __bf16* Pf  = (__bf16*)(ws + (size_t)N_NODES * 64 * 4);
        __bf16* Qf  = (__bf16*)(ws + (size_t)N_NODES * 64 * 4 + (size_t)N_NODES * 64 * 2);
        hipMemsetAsync(agg, 0, (size_t)N_NODES * 64 * 4, stream);
        pq_kernel_fb  <<<1563, 256, 0, stream>>>(nf, W1, b1, Pf, Qf);
        edge_kernel_fb<<<2048, 256, 0, stream>>>(ei, ef, W1, W2, b2, Pf, Qf, agg);
        gru_kernel    <<<1563, 256, 0, stream>>>(nf, agg, wih, whh, bih, bhh, nullptr, nullptr, out);
    }
}

// Round 6
// 514.557 us; speedup vs baseline: 1.2560x; 1.2560x over previous
//
#include <hip/hip_runtime.h>
#include <hip/hip_bf16.h>

#define N_NODES 100000
#define N_EDGES 1000000
#define SCAN_CHUNK 1024
#define N_SCAN_BLKS ((N_NODES + SCAN_CHUNK - 1) / SCAN_CHUNK)   // 98
#define NPB 256      // dst-sorted positions per msg block
#define HBST 72      // LDS row stride in bf16: 144B -> bank-stride 4, conflict-free
#define PQ_BLKS 1563
#define EFB_BLKS 2048
#define PREP_BLKS 48

typedef __bf16 bf16x8 __attribute__((ext_vector_type(8)));
typedef float  f32x4  __attribute__((ext_vector_type(4)));

#define MFMA(a, b, c) __builtin_amdgcn_mfma_f32_16x16x32_bf16((a), (b), (c), 0, 0, 0)

__device__ __forceinline__ float sigmoid_f(float x) { return 1.f / (1.f + __expf(-x)); }
__device__ __forceinline__ float tanh_f(float x) {
    float cx = fminf(fmaxf(x, -30.f), 30.f);
    float e = __expf(-2.f * cx);
    return (1.f - e) / (1.f + e);
}

// ---------------------------------------------------------------------------
// Histogram of dst
// ---------------------------------------------------------------------------
__global__ __launch_bounds__(256) void hist_kernel(
    const int* __restrict__ ei, int* __restrict__ cnt)
{
    const int* dstI = ei + N_EDGES;
    int i = (blockIdx.x * blockDim.x + threadIdx.x) * 4;
    if (i < N_EDGES) {
        int4 d4 = *(const int4*)&dstI[i];
        atomicAdd(&cnt[d4.x], 1);
        atomicAdd(&cnt[d4.y], 1);
        atomicAdd(&cnt[d4.z], 1);
        atomicAdd(&cnt[d4.w], 1);
    }
}

__global__ __launch_bounds__(256) void scanA_kernel(
    const int* __restrict__ cnt, int* __restrict__ blkSum)
{
    const int lane = threadIdx.x & 63, w = threadIdx.x >> 6;
    int base = blockIdx.x * SCAN_CHUNK + threadIdx.x * 4;
    int s = 0;
    #pragma unroll
    for (int j = 0; j < 4; ++j) if (base + j < N_NODES) s += cnt[base + j];
    #pragma unroll
    for (int o = 32; o > 0; o >>= 1) s += __shfl_down(s, o);
    __shared__ int wt[4];
    if (lane == 0) wt[w] = s;
    __syncthreads();
    if (threadIdx.x == 0) blkSum[blockIdx.x] = wt[0] + wt[1] + wt[2] + wt[3];
}

__global__ void scanB_kernel(int* __restrict__ blkSum)
{
    const int lane = threadIdx.x;
    int carry = 0;
    for (int c = 0; c < N_SCAN_BLKS; c += 64) {
        int v = (c + lane < N_SCAN_BLKS) ? blkSum[c + lane] : 0;
        int inc = v;
        #pragma unroll
        for (int o = 1; o < 64; o <<= 1) {
            int t = __shfl_up(inc, o);
            if (lane >= o) inc += t;
        }
        int ex = inc - v;
        if (c + lane < N_SCAN_BLKS) blkSum[c + lane] = carry + ex;
        carry += __shfl(inc, 63);
    }
}

__global__ __launch_bounds__(256) void scanC_kernel(
    const int* __restrict__ cnt, const int* __restrict__ blkSum,
    int* __restrict__ off, int* __restrict__ cur)
{
    const int lane = threadIdx.x & 63, w = threadIdx.x >> 6;
    int base = blockIdx.x * SCAN_CHUNK + threadIdx.x * 4;
    int v[4];
    int tsum = 0;
    #pragma unroll
    for (int j = 0; j < 4; ++j) {
        v[j] = (base + j < N_NODES) ? cnt[base + j] : 0;
        tsum += v[j];
    }
    int inc = tsum;
    #pragma unroll
    for (int o = 1; o < 64; o <<= 1) {
        int t = __shfl_up(inc, o);
        if (lane >= o) inc += t;
    }
    __shared__ int wt[4];
    if (lane == 63) wt[w] = inc;
    __syncthreads();
    int woff = 0;
    for (int k = 0; k < w; ++k) woff += wt[k];
    int running = blkSum[blockIdx.x] + woff + inc - tsum;
    #pragma unroll
    for (int j = 0; j < 4; ++j) {
        if (base + j < N_NODES) {
            off[base + j] = running;
            cur[base + j] = running;
            if (base + j == N_NODES - 1) off[N_NODES] = running + v[j];
            running += v[j];
        }
    }
}

// ---------------------------------------------------------------------------
// Fused precompute, block-range split:
//  [0, PQ_BLKS):      P/Q = nf @ W1[:,0:128]^T (+b1) -> bf16
//  [.., +EFB_BLKS):   per edge: p = cur[dst]++; slotSrc[p]=src;
//                     efb[p] = bf16(ef[e])   (scatter fused into convert)
//  [.., +PREP_BLKS):  M = w_ih@W2, b2i = w_ih@b2 (spread across 48 blocks)
// ---------------------------------------------------------------------------
__global__ __launch_bounds__(256) void pre_kernel(
    const float* __restrict__ nf, const float* __restrict__ W1,
    const float* __restrict__ b1, const float* __restrict__ ef,
    const int* __restrict__ ei, int* __restrict__ cur,
    const float* __restrict__ w_ih, const float* __restrict__ W2,
    const float* __restrict__ b2,
    __bf16* __restrict__ Pb, __bf16* __restrict__ Qb,
    __bf16* __restrict__ efb, int* __restrict__ slotSrc,
    float* __restrict__ M, float* __restrict__ b2i)
{
    const int b = blockIdx.x;
    if (b < PQ_BLKS) {
        const int lane = threadIdx.x & 63;
        const int r = lane & 15, g = lane >> 4;
        bf16x8 Bs[4][2], Bd[4][2];
        #pragma unroll
        for (int nt = 0; nt < 4; ++nt)
            #pragma unroll
            for (int kk = 0; kk < 2; ++kk) {
                const float* ws = &W1[(nt * 16 + r) * 160 + kk * 32 + g * 8];
                const float* wd = ws + 64;
                f32x4 s0 = *(const f32x4*)ws, s1 = *(const f32x4*)(ws + 4);
                f32x4 d0 = *(const f32x4*)wd, d1 = *(const f32x4*)(wd + 4);
                #pragma unroll
                for (int j = 0; j < 4; ++j) {
                    Bs[nt][kk][j] = (__bf16)s0[j]; Bs[nt][kk][j + 4] = (__bf16)s1[j];
                    Bd[nt][kk][j] = (__bf16)d0[j]; Bd[nt][kk][j + 4] = (__bf16)d1[j];
                }
            }
        float b1v[4];
        #pragma unroll
        for (int nt = 0; nt < 4; ++nt) b1v[nt] = b1[nt * 16 + r];

        const int wid = b * 4 + (threadIdx.x >> 6);
        const int nW  = PQ_BLKS * 4;
        for (int t = wid; t < N_NODES / 16; t += nW) {
            const int base = t * 16;
            bf16x8 A[2];
            #pragma unroll
            for (int kk = 0; kk < 2; ++kk) {
                const float* p = &nf[(size_t)(base + r) * 64 + kk * 32 + g * 8];
                f32x4 v0 = *(const f32x4*)p, v1 = *(const f32x4*)(p + 4);
                #pragma unroll
                for (int j = 0; j < 4; ++j) { A[kk][j] = (__bf16)v0[j]; A[kk][j + 4] = (__bf16)v1[j]; }
            }
            f32x4 accP[4] = {}, accQ[4] = {};
            #pragma unroll
            for (int nt = 0; nt < 4; ++nt)
                #pragma unroll
                for (int kk = 0; kk < 2; ++kk) {
                    accP[nt] = MFMA(A[kk], Bs[nt][kk], accP[nt]);
                    accQ[nt] = MFMA(A[kk], Bd[nt][kk], accQ[nt]);
                }
            #pragma unroll
            for (int nt = 0; nt < 4; ++nt)
                #pragma unroll
                for (int rr = 0; rr < 4; ++rr) {
                    const int node = base + g * 4 + rr;
                    const int col  = nt * 16 + r;
                    Pb[(size_t)node * 64 + col] = (__bf16)(accP[nt][rr] + b1v[nt]);
                    Qb[(size_t)node * 64 + col] = (__bf16)accQ[nt][rr];
                }
        }
    } else if (b < PQ_BLKS + EFB_BLKS) {
        const int* srcI = ei;
        const int* dstI = ei + N_EDGES;
        const int tid0 = (b - PQ_BLKS) * 256 + threadIdx.x;
        for (int e = tid0; e < N_EDGES; e += EFB_BLKS * 256) {
            int d = dstI[e], s = srcI[e];
            int p = atomicAdd(&cur[d], 1);
            slotSrc[p] = s;
            const float* ep = ef + (size_t)e * 32;
            __bf16* op = efb + (size_t)p * 32;
            #pragma unroll
            for (int c = 0; c < 4; ++c) {
                f32x4 v0 = *(const f32x4*)(ep + c * 8), v1 = *(const f32x4*)(ep + c * 8 + 4);
                bf16x8 v;
                #pragma unroll
                for (int j = 0; j < 4; ++j) { v[j] = (__bf16)v0[j]; v[j + 4] = (__bf16)v1[j]; }
                *(bf16x8*)(op + c * 8) = v;
            }
        }
    } else {
        const int pb = b - (PQ_BLKS + EFB_BLKS);
        for (int tid = pb * 256 + threadIdx.x; tid < 192 * 64; tid += PREP_BLKS * 256) {
            int d = tid >> 6, k = tid & 63;
            float s = 0.f;
            #pragma unroll 8
            for (int j = 0; j < 64; ++j) s += w_ih[d * 64 + j] * W2[j * 64 + k];
            M[tid] = s;
            if (tid < 192) {
                float s2 = 0.f;
                for (int j = 0; j < 64; ++j) s2 += w_ih[tid * 64 + j] * b2[j];
                b2i[tid] = s2;
            }
        }
    }
}

// ---------------------------------------------------------------------------
// Fused message kernel over dst-sorted positions (NPB=256).
// Phase A: T = efb@W1e^T via MFMA -> LDS h (bf16), efb read SEQUENTIAL.
// Phase B: per node, acc = sum relu(h + P[src] + Q[n]); plain store when the
// node's range is block-contained, else atomicAdd (Hsum pre-zeroed).
// ---------------------------------------------------------------------------
__global__ __launch_bounds__(256) void msg_kernel(
    const int* __restrict__ offA, const int* __restrict__ slotSrc,
    const __bf16* __restrict__ efb,
    const float* __restrict__ W1,
    const __bf16* __restrict__ Pb, const __bf16* __restrict__ Qb,
    float* __restrict__ Hsum)
{
    __shared__ __bf16 h[NPB * HBST];   // 36 KiB -> 4 blocks/CU
    __shared__ int nlo_s;
    const int p0 = blockIdx.x * NPB;
    const int p1 = min(p0 + NPB, N_EDGES);
    const int cntP = p1 - p0;
    const int lane = threadIdx.x & 63;
    const int w = threadIdx.x >> 6;
    const int r = lane & 15, g = lane >> 4;

    bf16x8 Be[4];
    #pragma unroll
    for (int nt = 0; nt < 4; ++nt) {
        const float* wp = &W1[(nt * 16 + r) * 160 + 128 + g * 8];
        f32x4 w0 = *(const f32x4*)wp, w1 = *(const f32x4*)(wp + 4);
        #pragma unroll
        for (int j = 0; j < 4; ++j) { Be[nt][j] = (__bf16)w0[j]; Be[nt][j + 4] = (__bf16)w1[j]; }
    }

    if (threadIdx.x == 0) {
        int lo = 0, hi = N_NODES - 1;
        while (lo < hi) { int mid = (lo + hi) >> 1; if (offA[mid + 1] > p0) hi = mid; else lo = mid + 1; }
        nlo_s = lo;
    }

    // ---- phase A: sequential efb rows, MFMA, bf16 h to LDS ----
    const int ntile = cntP >> 4;     // cntP is a multiple of 16
    for (int t = w; t < ntile; t += 4) {
        bf16x8 Ae = *(const bf16x8*)&efb[(size_t)(p0 + t * 16 + r) * 32 + g * 8];
        f32x4 accT[4] = {};
        #pragma unroll
        for (int nt = 0; nt < 4; ++nt) accT[nt] = MFMA(Ae, Be[nt], accT[nt]);
        #pragma unroll
        for (int nt = 0; nt < 4; ++nt)
            #pragma unroll
            for (int rr = 0; rr < 4; ++rr)
                h[(t * 16 + g * 4 + rr) * HBST + nt * 16 + r] = (__bf16)accT[nt][rr];
    }
    __syncthreads();

    // ---- phase B ----
    const int nlo = nlo_s;
    for (int n = nlo + w; n < N_NODES; n += 4) {
        const int on0 = offA[n], on1 = offA[n + 1];
        if (on0 >= p1) break;
        const int lo_ = max(on0, p0), hi_ = min(on1, p1);
        const int m = hi_ - lo_;
        if (m <= 0) continue;
        const int lb = lo_ - p0;
        float q = (float)Qb[(size_t)n * 64 + lane];
        float acc = 0.f;
        int sl = (lane < m) ? slotSrc[lo_ + lane] : 0;
        int i = 0;
        for (; i + 8 <= m && i + 8 <= 64; i += 8) {
            float pv[8], hv[8];
            #pragma unroll
            for (int j = 0; j < 8; ++j) {
                int s = __shfl(sl, i + j);
                pv[j] = (float)Pb[(size_t)s * 64 + lane];
                hv[j] = (float)h[(lb + i + j) * HBST + lane];
            }
            #pragma unroll
            for (int j = 0; j < 8; ++j)
                acc += fmaxf(hv[j] + pv[j] + q, 0.f);
        }
        for (; i < m; ++i) {
            int s = (i < 64) ? __shfl(sl, i) : slotSrc[lo_ + i];
            acc += fmaxf((float)h[(lb + i) * HBST + lane] + (float)Pb[(size_t)s * 64 + lane] + q, 0.f);
        }
        if (on0 >= p0 && on1 <= p1) Hsum[(size_t)n * 64 + lane] = acc;
        else                        atomicAdd(&Hsum[(size_t)n * 64 + lane], acc);
    }
}

// ---------------------------------------------------------------------------
// GRU (weights in LDS as bf16, XOR-swizzled; split-bf16 A hi+lo)
// ---------------------------------------------------------------------------
__global__ __launch_bounds__(256) void gru_kernel(
    const float* __restrict__ nf, const float* __restrict__ Hsum,
    const float* __restrict__ M, const float* __restrict__ w_hh,
    const float* __restrict__ b_ih, const float* __restrict__ b_hh,
    const float* __restrict__ b2i, const int* __restrict__ cnt,
    float* __restrict__ out)
{
    __shared__ __bf16 w_lds[2 * 192 * 64];
    for (int ch = threadIdx.x; ch < 3072; ch += 256) {
        int mat = ch / 1536;
        int rr  = (ch - mat * 1536) >> 3;
        int cc  = ch & 7;
        const float* sp = (mat == 0 ? M : w_hh) + rr * 64 + cc * 8;
        f32x4 a = *(const f32x4*)sp, b = *(const f32x4*)(sp + 4);
        bf16x8 v;
        #pragma unroll
        for (int j = 0; j < 4; ++j) { v[j] = (__bf16)a[j]; v[j + 4] = (__bf16)b[j]; }
        *(bf16x8*)&w_lds[((mat * 192 + rr) * 64) + ((cc ^ (rr & 7)) * 8)] = v;
    }
    __syncthreads();

    const int lane = threadIdx.x & 63;
    const int r = lane & 15, g = lane >> 4;
    const int wid = blockIdx.x * (blockDim.x >> 6) + (threadIdx.x >> 6);
    const int nW  = gridDim.x * (blockDim.x >> 6);

    float br[4], bz[4], bin_[4], bhn_[4], c2r[4], c2z[4], c2n[4];
    #pragma unroll
    for (int nt = 0; nt < 4; ++nt) {
        const int d = nt * 16 + r;
        br[nt]   = b_ih[d] + b_hh[d];
        bz[nt]   = b_ih[64 + d] + b_hh[64 + d];
        bin_[nt] = b_ih[128 + d];
        bhn_[nt] = b_hh[128 + d];
        c2r[nt] = b2i ? b2i[d] : 0.f;
        c2z[nt] = b2i ? b2i[64 + d] : 0.f;
        c2n[nt] = b2i ? b2i[128 + d] : 0.f;
    }
    const int swz = r & 7;

    for (int t = wid; t < N_NODES / 16; t += nW) {
        const int base = t * 16;
        bf16x8 aaH[2], aaL[2], ahH[2], ahL[2];
        #pragma unroll
        for (int kk = 0; kk < 2; ++kk) {
            const float* pa = &Hsum[(size_t)(base + r) * 64 + kk * 32 + g * 8];
            const float* ph = &nf  [(size_t)(base + r) * 64 + kk * 32 + g * 8];
            f32x4 a0 = *(const f32x4*)pa, a1 = *(const f32x4*)(pa + 4);
            f32x4 h0 = *(const f32x4*)ph, h1 = *(const f32x4*)(ph + 4);
            #pragma unroll
            for (int j = 0; j < 4; ++j) {
                float av0 = a0[j], av1 = a1[j], hv0 = h0[j], hv1 = h1[j];
                __bf16 x;
                x = (__bf16)av0; aaH[kk][j]     = x; aaL[kk][j]     = (__bf16)(av0 - (float)x);
                x = (__bf16)av1; aaH[kk][j + 4] = x; aaL[kk][j + 4] = (__bf16)(av1 - (float)x);
                x = (__bf16)hv0; ahH[kk][j]     = x; ahL[kk][j]     = (__bf16)(hv0 - (float)x);
                x = (__bf16)hv1; ahH[kk][j + 4] = x; ahL[kk][j + 4] = (__bf16)(hv1 - (float)x);
            }
        }

        f32x4 accR[4] = {}, accZ[4] = {}, accIN[4] = {}, accHN[4] = {};
        #pragma unroll
        for (int c = 0; c < 3; ++c)
            #pragma unroll
            for (int nt = 0; nt < 4; ++nt) {
                const int row = c * 64 + nt * 16 + r;
                f32x4 ai = {}, ah = {};
                #pragma unroll
                for (int kk = 0; kk < 2; ++kk) {
                    const int cc = (kk * 4 + g) ^ swz;
                    bf16x8 Bi = *(const bf16x8*)&w_lds[row * 64 + cc * 8];
                    bf16x8 Bh = *(const bf16x8*)&w_lds[(192 + row) * 64 + cc * 8];
                    ai = MFMA(aaH[kk], Bi, ai);
                    ai = MFMA(aaL[kk], Bi, ai);
                    ah = MFMA(ahH[kk], Bh, ah);
                    ah = MFMA(ahL[kk], Bh, ah);
                }
                if (c == 0)      accR[nt] = ai + ah;
                else if (c == 1) accZ[nt] = ai + ah;
                else             { accIN[nt] = ai; accHN[nt] = ah; }
            }
        #pragma unroll
        for (int nt = 0; nt < 4; ++nt)
            #pragma unroll
            for (int rr = 0; rr < 4; ++rr) {
                const int node = base + g * 4 + rr;
                const int d    = nt * 16 + r;
                float dg = cnt ? (float)cnt[node] : 0.f;
                float rg = sigmoid_f(accR[nt][rr] + br[nt] + dg * c2r[nt]);
                float zg = sigmoid_f(accZ[nt][rr] + bz[nt] + dg * c2z[nt]);
                float ng = tanh_f(accIN[nt][rr] + bin_[nt] + dg * c2n[nt] +
                                  rg * (accHN[nt][rr] + bhn_[nt]));
                float hv = nf[(size_t)node * 64 + d];
                out[(size_t)node * 64 + d] = (1.f - zg) * ng + zg * hv;
            }
    }
}

// ---------------------------------------------------------------------------
// Fallback path kernels (unused when ws is large enough)
// ---------------------------------------------------------------------------
__global__ __launch_bounds__(256) void pq_kernel_fb(
    const float* __restrict__ nf, const float* __restrict__ W1,
    const float* __restrict__ b1,
    __bf16* __restrict__ Pb, __bf16* __restrict__ Qb)
{
    const int lane = threadIdx.x & 63;
    const int r = lane & 15, g = lane >> 4;
    bf16x8 Bs[4][2], Bd[4][2];
    #pragma unroll
    for (int nt = 0; nt < 4; ++nt)
        #pragma unroll
        for (int kk = 0; kk < 2; ++kk) {
            const float* ws = &W1[(nt * 16 + r) * 160 + kk * 32 + g * 8];
            const float* wd = ws + 64;
            f32x4 s0 = *(const f32x4*)ws, s1 = *(const f32x4*)(ws + 4);
            f32x4 d0 = *(const f32x4*)wd, d1 = *(const f32x4*)(wd + 4);
            #pragma unroll
            for (int j = 0; j < 4; ++j) {
                Bs[nt][kk][j] = (__bf16)s0[j]; Bs[nt][kk][j + 4] = (__bf16)s1[j];
                Bd[nt][kk][j] = (__bf16)d0[j]; Bd[nt][kk][j + 4] = (__bf16)d1[j];
            }
        }
    float b1v[4];
    #pragma unroll
    for (int nt = 0; nt < 4; ++nt) b1v[nt] = b1[nt * 16 + r];
    const int wid = blockIdx.x * 4 + (threadIdx.x >> 6);
    const int nW  = gridDim.x * 4;
    for (int t = wid; t < N_NODES / 16; t += nW) {
        const int base = t * 16;
        bf16x8 A[2];
        #pragma unroll
        for (int kk = 0; kk < 2; ++kk) {
            const float* p = &nf[(size_t)(base + r) * 64 + kk * 32 + g * 8];
            f32x4 v0 = *(const f32x4*)p, v1 = *(const f32x4*)(p + 4);
            #pragma unroll
            for (int j = 0; j < 4; ++j) { A[kk][j] = (__bf16)v0[j]; A[kk][j + 4] = (__bf16)v1[j]; }
        }
        f32x4 accP[4] = {}, accQ[4] = {};
        #pragma unroll
        for (int nt = 0; nt < 4; ++nt)
            #pragma unroll
            for (int kk = 0; kk < 2; ++kk) {
                accP[nt] = MFMA(A[kk], Bs[nt][kk], accP[nt]);
                accQ[nt] = MFMA(A[kk], Bd[nt][kk], accQ[nt]);
            }
        #pragma unroll
        for (int nt = 0; nt < 4; ++nt)
            #pragma unroll
            for (int rr = 0; rr < 4; ++rr) {
                const int node = base + g * 4 + rr;
                const int col  = nt * 16 + r;
                Pb[(size_t)node * 64 + col] = (__bf16)(accP[nt][rr] + b1v[nt]);
                Qb[(size_t)node * 64 + col] = (__bf16)accQ[nt][rr];
            }
    }
}

#define LDH 68
__global__ __launch_bounds__(256) void edge_kernel_fb(
    const int* __restrict__ ei, const float* __restrict__ ef,
    const float* __restrict__ W1, const float* __restrict__ W2,
    const float* __restrict__ b2,
    const __bf16* __restrict__ Pb, const __bf16* __restrict__ Qb,
    float* __restrict__ agg)
{
    __shared__ float lds_h[4][16 * LDH];
    const int lane = threadIdx.x & 63;
    const int r = lane & 15, g = lane >> 4;
    float* hb = lds_h[threadIdx.x >> 6];
    const int* srcI = ei;
    const int* dstI = ei + N_EDGES;
    bf16x8 Be[4];
    #pragma unroll
    for (int nt = 0; nt < 4; ++nt) {
        const float* wp = &W1[(nt * 16 + r) * 160 + 128 + g * 8];
        f32x4 w0 = *(const f32x4*)wp, w1 = *(const f32x4*)(wp + 4);
        #pragma unroll
        for (int j = 0; j < 4; ++j) { Be[nt][j] = (__bf16)w0[j]; Be[nt][j + 4] = (__bf16)w1[j]; }
    }
    bf16x8 B2[4][2];
    #pragma unroll
    for (int nt = 0; nt < 4; ++nt)
        #pragma unroll
        for (int kk = 0; kk < 2; ++kk) {
            const float* wp = &W2[(nt * 16 + r) * 64 + kk * 32 + g * 8];
            f32x4 w0 = *(const f32x4*)wp, w1 = *(const f32x4*)(wp + 4);
            #pragma unroll
            for (int j = 0; j < 4; ++j) { B2[nt][kk][j] = (__bf16)w0[j]; B2[nt][kk][j + 4] = (__bf16)w1[j]; }
        }
    float b2v[4];
    #pragma unroll
    for (int nt = 0; nt < 4; ++nt) b2v[nt] = b2[nt * 16 + r];
    const int wid = blockIdx.x * 4 + (threadIdx.x >> 6);
    const int nW  = gridDim.x * 4;
    for (int t = wid; t < N_EDGES / 16; t += nW) {
        const int base = t * 16;
        const int er = base + r;
        const int es = srcI[er], ed = dstI[er];
        bf16x8 Ae;
        {
            const float* p = &ef[(size_t)er * 32 + g * 8];
            f32x4 v0 = *(const f32x4*)p, v1 = *(const f32x4*)(p + 4);
            #pragma unroll
            for (int j = 0; j < 4; ++j) { Ae[j] = (__bf16)v0[j]; Ae[j + 4] = (__bf16)v1[j]; }
        }
        f32x4 accT[4] = {};
        #pragma unroll
        for (int nt = 0; nt < 4; ++nt) accT[nt] = MFMA(Ae, Be[nt], accT[nt]);
        #pragma unroll
        for (int nt = 0; nt < 4; ++nt)
            #pragma unroll
            for (int rr = 0; rr < 4; ++rr)
                hb[(g * 4 + rr) * LDH + nt * 16 + r] = accT[nt][rr];
        bf16x8 A2[2];
        #pragma unroll
        for (int kk = 0; kk < 2; ++kk) {
            const int k = kk * 32 + g * 8;
            const float* hp = &hb[r * LDH + k];
            f32x4 h0 = *(const f32x4*)hp, h1 = *(const f32x4*)(hp + 4);
            bf16x8 p8 = *(const bf16x8*)(Pb + (size_t)es * 64 + k);
            bf16x8 q8 = *(const bf16x8*)(Qb + (size_t)ed * 64 + k);
            #pragma unroll
            for (int j = 0; j < 4; ++j) {
                A2[kk][j]     = (__bf16)fmaxf(h0[j] + (float)p8[j]     + (float)q8[j],     0.f);
                A2[kk][j + 4] = (__bf16)fmaxf(h1[j] + (float)p8[j + 4] + (float)q8[j + 4], 0.f);
            }
        }
        f32x4 accM[4] = {};
        #pragma unroll
        for (int nt = 0; nt < 4; ++nt)
            #pragma unroll
            for (int kk = 0; kk < 2; ++kk)
                accM[nt] = MFMA(A2[kk], B2[nt][kk], accM[nt]);
        int4 d4 = *(const int4*)(dstI + base + g * 4);
        const int* dd = (const int*)&d4;
        #pragma unroll
        for (int rr = 0; rr < 4; ++rr) {
            float* dp = agg + (size_t)dd[rr] * 64;
            #pragma unroll
            for (int nt = 0; nt < 4; ++nt)
                atomicAdd(dp + nt * 16 + r, accM[nt][rr] + b2v[nt]);
        }
    }
}

extern "C" void kernel_launch(void* const* d_in, const int* in_sizes, int n_in,
                              void* d_out, int out_size, void* d_ws, size_t ws_size,
                              hipStream_t stream) {
    const float* nf  = (const float*)d_in[0];
    const int*   ei  = (const int*)  d_in[1];
    const float* ef  = (const float*)d_in[2];
    const float* W1  = (const float*)d_in[3];
    const float* b1  = (const float*)d_in[4];
    const float* W2  = (const float*)d_in[5];
    const float* b2  = (const float*)d_in[6];
    const float* wih = (const float*)d_in[7];
    const float* whh = (const float*)d_in[8];
    const float* bih = (const float*)d_in[9];
    const float* bhh = (const float*)d_in[10];
    float* out = (float*)d_out;

    char* ws = (char*)d_ws;
    size_t off_b = 0;
    auto alloc = [&](size_t bytes) { char* p = ws + off_b; off_b = (off_b + bytes + 255) & ~(size_t)255; return p; };
    int*    cnt     = (int*)   alloc((size_t)N_NODES * 4);
    int*    offA    = (int*)   alloc((size_t)(N_NODES + 1) * 4);
    int*    cur     = (int*)   alloc((size_t)N_NODES * 4);
    int*    blkSum  = (int*)   alloc((size_t)N_SCAN_BLKS * 4);
    int*    slotSrc = (int*)   alloc((size_t)N_EDGES * 4);        // 4 MB
    __bf16* efb     = (__bf16*)alloc((size_t)N_EDGES * 32 * 2);   // 64 MB, dst-sorted
    __bf16* Pb      = (__bf16*)alloc((size_t)N_NODES * 64 * 2);   // 12.8 MB
    __bf16* Qb      = (__bf16*)alloc((size_t)N_NODES * 64 * 2);
    float*  Hsum    = (float*) alloc((size_t)N_NODES * 64 * 4);   // 25.6 MB
    float*  M       = (float*) alloc((size_t)192 * 64 * 4);
    float*  b2i     = (float*) alloc((size_t)192 * 4);
    const size_t need = off_b;

    if (ws_size >= need) {
        hipMemsetAsync(cnt, 0, (size_t)N_NODES * 4, stream);
        hipMemsetAsync(Hsum, 0, (size_t)N_NODES * 64 * 4, stream);
        hist_kernel   <<<(N_EDGES / 4 + 255) / 256, 256, 0, stream>>>(ei, cnt);
        scanA_kernel  <<<N_SCAN_BLKS, 256, 0, stream>>>(cnt, blkSum);
        scanB_kernel  <<<1, 64, 0, stream>>>(blkSum);
        scanC_kernel  <<<N_SCAN_BLKS, 256, 0, stream>>>(cnt, blkSum, offA, cur);
        pre_kernel    <<<PQ_BLKS + EFB_BLKS + PREP_BLKS, 256, 0, stream>>>(
                          nf, W1, b1, ef, ei, cur, wih, W2, b2,
                          Pb, Qb, efb, slotSrc, M, b2i);
        msg_kernel    <<<(N_EDGES + NPB - 1) / NPB, 256, 0, stream>>>(
                          offA, slotSrc, efb, W1, Pb, Qb, Hsum);
        gru_kernel    <<<1563, 256, 0, stream>>>(nf, Hsum, M, whh, bih, bhh, b2i, cnt, out);
    } else {
        float*  agg = (float*)ws;
        __bf16* Pf  = (__bf16*)(ws + (size_t)N_NODES * 64 * 4);
        __bf16* Qf  = (__bf16*)(ws + (size_t)N_NODES * 64 * 4 + (size_t)N_NODES * 64 * 2);
        hipMemsetAsync(agg, 0, (size_t)N_NODES * 64 * 4, stream);
        pq_kernel_fb  <<<1563, 256, 0, stream>>>(nf, W1, b1, Pf, Qf);
        edge_kernel_fb<<<2048, 256, 0, stream>>>(ei, ef, W1, W2, b2, Pf, Qf, agg);
        gru_kernel    <<<1563, 256, 0, stream>>>(nf, agg, wih, whh, bih, bhh, nullptr, nullptr, out);
    }
}